// Round 1
// baseline (1012.830 us; speedup 1.0000x reference)
//
#include <hip/hip_runtime.h>

// RGCN 2-layer, basis decomposition, mean aggregation.
// N=50000 nodes, E=1.6M edges, R=8 relations, feat 128->128->64.
//
// Strategy:
//  1) compose W_r = sum_b comp[r,b]*basis[b]  (tiny kernel, both layers)
//  2) build padded-CSR (ELL, CAP=32) via int atomics: cnt[seg], ell[seg*CAP+slot]=src
//     seg = rel*N + dst. Poisson(4) max over 400k segs ~18 << 32, no overflow.
//  3) per layer: fused kernel, 64-node tile/block, loop r=0..8 (8 = root):
//     gather-mean into LDS meanT[64][132], W chunk (32 rows) into LDS,
//     8x8(or 8x4) register-tile f32 GEMM accumulating over r. ReLU+bias epilogue.
//  No (R,N,C) intermediate ever hits HBM; no float atomics.

#define N_NODES 50000
#define N_EDGES 1600000
#define N_REL   8
#define CAP     32

__global__ void zero_i32_kernel(int* __restrict__ p, int n) {
    int i = blockIdx.x * 256 + threadIdx.x;
    if (i < n) p[i] = 0;
}

// W[r, k] = sum_b comp[r,b] * basis[b, k],  k in [0, io_total)
__global__ void compose_w_kernel(const float* __restrict__ basis,
                                 const float* __restrict__ comp,
                                 float* __restrict__ W,
                                 int nbases, int io_total, int total) {
    int k = blockIdx.x * 256 + threadIdx.x;
    if (k >= total) return;
    int r = k / io_total;
    int j = k - r * io_total;
    float s = 0.f;
    for (int b = 0; b < nbases; ++b)
        s += comp[r * nbases + b] * basis[b * io_total + j];
    W[k] = s;
}

__global__ void build_ell_kernel(const int* __restrict__ A,      // (2,E) src then dst
                                 const int* __restrict__ etype,  // (E,)
                                 int* __restrict__ cnt,          // (R*N,)
                                 int* __restrict__ ell) {        // (R*N, CAP)
    int e = blockIdx.x * 256 + threadIdx.x;
    if (e >= N_EDGES) return;
    int s = A[e];
    int d = A[N_EDGES + e];
    int t = etype[e];
    int seg = t * N_NODES + d;
    int slot = atomicAdd(&cnt[seg], 1);
    if (slot < CAP) ell[seg * CAP + slot] = s;
}

// Fused mean-aggregate + per-relation GEMM + root + bias (+relu).
// Block = 128 threads, node tile TN=64.
// r in [0, N_REL]: r==N_REL is the root/self term (mean := input row).
template <int OUTC, bool RELU>
__global__ __launch_bounds__(128)
void rgcn_layer_kernel(const float* __restrict__ xin,   // (N,128)
                       const int* __restrict__ cnt,     // (R*N,)
                       const int* __restrict__ ell,     // (R*N,CAP)
                       const float* __restrict__ Wrel,  // (R,128,OUTC)
                       const float* __restrict__ Wroot, // (128,OUTC)
                       const float* __restrict__ bias,  // (OUTC,)
                       float* __restrict__ out) {       // (N,OUTC)
    constexpr int INC = 128;
    constexpr int TN  = 64;
    constexpr int ICH = 32;                    // W chunk rows in LDS
    constexpr int TO  = (OUTC == 128) ? 8 : 4; // outs per thread
    constexpr int LDM = INC + 4;               // meanT row stride (pad: 132%32=4 banks)

    __shared__ float meanT[TN * LDM];          // 33.8 KB
    __shared__ float Wl[ICH * OUTC];           // 16 KB (L1) / 8 KB (L2)

    const int tid   = threadIdx.x;
    const int nbase = blockIdx.x * TN;

    // GEMM mapping: wave lanes 0..63 -> og=tid>>3 (out group), ng=tid&7.
    // Thread owns nodes {ng + 8*nn} and outs [og*TO, og*TO+TO).
    const int og = tid >> 3;
    const int ng = tid & 7;
    const int o0 = og * TO;

    // Aggregation mapping: 2 threads per node, 64 features each.
    const int anode = tid >> 1;
    const int ahalf = tid & 1;
    const int gnode = nbase + anode;

    float acc[8][TO];
#pragma unroll
    for (int a = 0; a < 8; ++a)
#pragma unroll
        for (int b = 0; b < TO; ++b) acc[a][b] = 0.f;

    for (int r = 0; r <= N_REL; ++r) {
        __syncthreads();  // prior GEMM finished reading meanT
        // ---- aggregation: mean_r for 64 nodes into meanT ----
        {
            float4 av[16];
#pragma unroll
            for (int k = 0; k < 16; ++k) av[k] = make_float4(0.f, 0.f, 0.f, 0.f);
            if (gnode < N_NODES) {
                if (r == N_REL) {  // root: copy own row
                    const float4* xr =
                        (const float4*)(xin + (size_t)gnode * INC + ahalf * 64);
#pragma unroll
                    for (int k = 0; k < 16; ++k) av[k] = xr[k];
                } else {
                    int seg = r * N_NODES + gnode;
                    int c  = cnt[seg];
                    int cu = c < CAP ? c : CAP;
                    const int* el = ell + seg * CAP;
                    for (int j = 0; j < cu; ++j) {
                        int idx = el[j];
                        const float4* xr =
                            (const float4*)(xin + (size_t)idx * INC + ahalf * 64);
#pragma unroll
                        for (int k = 0; k < 16; ++k) {
                            float4 v = xr[k];
                            av[k].x += v.x; av[k].y += v.y;
                            av[k].z += v.z; av[k].w += v.w;
                        }
                    }
                    float inv = 1.f / (float)(c > 1 ? c : 1);
#pragma unroll
                    for (int k = 0; k < 16; ++k) {
                        av[k].x *= inv; av[k].y *= inv;
                        av[k].z *= inv; av[k].w *= inv;
                    }
                }
            }
            float4* mrow = (float4*)&meanT[anode * LDM + ahalf * 64];
#pragma unroll
            for (int k = 0; k < 16; ++k) mrow[k] = av[k];
        }

        const float* Wsrc = (r == N_REL) ? Wroot : (Wrel + r * (INC * OUTC));
        for (int ic = 0; ic < INC; ic += ICH) {
            __syncthreads();  // meanT ready / previous Wl chunk consumed
            {   // stage W chunk (coalesced float4)
                const float4* wsp = (const float4*)(Wsrc + ic * OUTC);
                float4* wd = (float4*)Wl;
                constexpr int NV = ICH * OUTC / 4;
#pragma unroll
                for (int k = 0; k < NV / 128; ++k) wd[tid + k * 128] = wsp[tid + k * 128];
            }
            __syncthreads();
#pragma unroll
            for (int i4 = 0; i4 < ICH; i4 += 4) {
                float4 a4[8];
#pragma unroll
                for (int nn = 0; nn < 8; ++nn)
                    a4[nn] = *(const float4*)&meanT[(ng + nn * 8) * LDM + ic + i4];
#pragma unroll
                for (int s = 0; s < 4; ++s) {
                    float4 w0 = *(const float4*)&Wl[(i4 + s) * OUTC + o0];
                    float4 w1;
                    if constexpr (TO == 8)
                        w1 = *(const float4*)&Wl[(i4 + s) * OUTC + o0 + 4];
#pragma unroll
                    for (int nn = 0; nn < 8; ++nn) {
                        float a = (s == 0) ? a4[nn].x
                                : (s == 1) ? a4[nn].y
                                : (s == 2) ? a4[nn].z : a4[nn].w;
                        acc[nn][0] += a * w0.x;
                        acc[nn][1] += a * w0.y;
                        acc[nn][2] += a * w0.z;
                        acc[nn][3] += a * w0.w;
                        if constexpr (TO == 8) {
                            acc[nn][4] += a * w1.x;
                            acc[nn][5] += a * w1.y;
                            acc[nn][6] += a * w1.z;
                            acc[nn][7] += a * w1.w;
                        }
                    }
                }
            }
        }
    }

    // ---- epilogue: bias (+relu), float4 stores ----
    float4 bv0 = *(const float4*)&bias[o0];
    float4 bv1 = make_float4(0.f, 0.f, 0.f, 0.f);
    if constexpr (TO == 8) bv1 = *(const float4*)&bias[o0 + 4];
#pragma unroll
    for (int nn = 0; nn < 8; ++nn) {
        int node = nbase + ng + nn * 8;
        if (node < N_NODES) {
            float4 v0 = make_float4(acc[nn][0] + bv0.x, acc[nn][1] + bv0.y,
                                    acc[nn][2] + bv0.z, acc[nn][3] + bv0.w);
            if constexpr (RELU) {
                v0.x = fmaxf(v0.x, 0.f); v0.y = fmaxf(v0.y, 0.f);
                v0.z = fmaxf(v0.z, 0.f); v0.w = fmaxf(v0.w, 0.f);
            }
            *(float4*)&out[(size_t)node * OUTC + o0] = v0;
            if constexpr (TO == 8) {
                float4 v1 = make_float4(acc[nn][4] + bv1.x, acc[nn][5] + bv1.y,
                                        acc[nn][6] + bv1.z, acc[nn][7] + bv1.w);
                if constexpr (RELU) {
                    v1.x = fmaxf(v1.x, 0.f); v1.y = fmaxf(v1.y, 0.f);
                    v1.z = fmaxf(v1.z, 0.f); v1.w = fmaxf(v1.w, 0.f);
                }
                *(float4*)&out[(size_t)node * OUTC + o0 + 4] = v1;
            }
        }
    }
}

extern "C" void kernel_launch(void* const* d_in, const int* in_sizes, int n_in,
                              void* d_out, int out_size, void* d_ws, size_t ws_size,
                              hipStream_t stream) {
    const float* x        = (const float*)d_in[0];
    const int*   A        = (const int*)d_in[1];   // (2,E) int32
    const int*   etype    = (const int*)d_in[2];   // (E,)  int32
    const float* w1_basis = (const float*)d_in[3];
    const float* w1_comp  = (const float*)d_in[4];
    const float* w1_root  = (const float*)d_in[5];
    const float* w1_bias  = (const float*)d_in[6];
    const float* w2_basis = (const float*)d_in[7];
    const float* w2_comp  = (const float*)d_in[8];
    const float* w2_root  = (const float*)d_in[9];
    const float* w2_bias  = (const float*)d_in[10];
    float* out = (float*)d_out;

    // workspace layout (all re-initialized every call; ws is poisoned 0xAA)
    char* ws = (char*)d_ws;
    float* W1c = (float*)(ws);                  // 512 KB composed W1 (8,128,128)
    float* W2c = (float*)(ws + (512 << 10));    // 256 KB composed W2 (8,128,64)
    int*   cnt = (int*)(ws + (768 << 10));      // 1.6 MB counts (R*N)
    int*   ell = (int*)(ws + (4ull << 20));     // 51.2 MB ELL (R*N*CAP)
    float* h   = (float*)(ws + (64ull << 20));  // 25.6 MB hidden (N,128)

    zero_i32_kernel<<<(N_REL * N_NODES + 255) / 256, 256, 0, stream>>>(
        cnt, N_REL * N_NODES);
    compose_w_kernel<<<(N_REL * 128 * 128 + 255) / 256, 256, 0, stream>>>(
        w1_basis, w1_comp, W1c, 4, 128 * 128, N_REL * 128 * 128);
    compose_w_kernel<<<(N_REL * 128 * 64 + 255) / 256, 256, 0, stream>>>(
        w2_basis, w2_comp, W2c, 4, 128 * 64, N_REL * 128 * 64);
    build_ell_kernel<<<(N_EDGES + 255) / 256, 256, 0, stream>>>(A, etype, cnt, ell);

    int grid = (N_NODES + 63) / 64;
    rgcn_layer_kernel<128, true><<<grid, 128, 0, stream>>>(
        x, cnt, ell, W1c, w1_root, w1_bias, h);
    rgcn_layer_kernel<64, false><<<grid, 128, 0, stream>>>(
        h, cnt, ell, W2c, w2_root, w2_bias, out);
}

// Round 4
// 432.025 us; speedup vs baseline: 2.3444x; 2.3444x over previous
//
#include <hip/hip_runtime.h>

// RGCN 2-layer, basis decomposition, mean aggregation - MFMA + bf16-gather.
// N=50000, E=1.6M, R=8, feat 128->128->64.
//
//  1) convert x -> bf16 rows (N+1 rows, row N = zeros = gather sentinel)
//  2) compose W_r^T (+root^T) to bf16 (R+1, OUTC, 128); build ELL (CAP=32)
//  3) per layer fused kernel (32-node tile, 256 thr):
//     r in [0..8] (8=root): 16-lane/node gather-mean of bf16 rows, 4-deep
//     branch-free inner loop (zero-row padding), f32 accum -> bf16 LDS
//     meanT[32][136]; W_r^T bf16 LDS; 4 waves 16x16x32 bf16 MFMA accum over r.
//     Layer1 writes h in bf16 (feeds layer2's gather + MFMA directly).

#define N_NODES 50000
#define N_EDGES 1600000
#define N_REL   8
#define CAP     32

typedef __attribute__((ext_vector_type(8))) short short8;
typedef __attribute__((ext_vector_type(4))) float f32x4;

__device__ __forceinline__ ushort f2bf(float x) {
    unsigned u = __builtin_bit_cast(unsigned, x);
    u += 0x7FFFu + ((u >> 16) & 1u);   // RNE
    return (ushort)(u >> 16);
}
__device__ __forceinline__ float u2f(unsigned u) {
    return __builtin_bit_cast(float, u);
}

__global__ void zero_i32_kernel(int* __restrict__ p, int n) {
    int i = blockIdx.x * 256 + threadIdx.x;
    if (i < n) p[i] = 0;
}

// x (N,128) f32 -> xbf ((N+1),128) bf16, row N zeroed (gather sentinel).
__global__ void to_bf16_kernel(const float* __restrict__ in,
                               ushort* __restrict__ out) {
    int i = blockIdx.x * 256 + threadIdx.x;            // one 8-elem strip
    int total = (N_NODES + 1) * 16;
    if (i >= total) return;
    int base = i * 8;
    short8 v;
    if (base < N_NODES * 128) {
        f32x4 a = *(const f32x4*)(in + base);
        f32x4 b = *(const f32x4*)(in + base + 4);
        v = (short8){(short)f2bf(a.x), (short)f2bf(a.y), (short)f2bf(a.z),
                     (short)f2bf(a.w), (short)f2bf(b.x), (short)f2bf(b.y),
                     (short)f2bf(b.z), (short)f2bf(b.w)};
    } else {
        v = (short8){0, 0, 0, 0, 0, 0, 0, 0};
    }
    *(short8*)(out + base) = v;
}

// Wt[(r*outc + n)*128 + k] = bf16( sum_b comp[r,b]*basis[b,k,n] ), r==8 -> root
__global__ void compose_wt_kernel(const float* __restrict__ basis,
                                  const float* __restrict__ comp,
                                  const float* __restrict__ root,
                                  ushort* __restrict__ Wt,
                                  int outc, int total) {
    int i = blockIdx.x * 256 + threadIdx.x;
    if (i >= total) return;
    int per_r = outc << 7;
    int r = i / per_r;
    int rem = i - r * per_r;
    int n = rem >> 7;
    int k = rem & 127;
    float s;
    if (r == N_REL) {
        s = root[k * outc + n];
    } else {
        s = 0.f;
#pragma unroll
        for (int b = 0; b < 4; ++b)
            s += comp[r * 4 + b] * basis[(b * 128 + k) * outc + n];
    }
    Wt[i] = f2bf(s);
}

__global__ void build_ell_kernel(const int* __restrict__ A,
                                 const int* __restrict__ etype,
                                 int* __restrict__ cnt,
                                 int* __restrict__ ell) {
    int e = blockIdx.x * 256 + threadIdx.x;
    if (e >= N_EDGES) return;
    int s = A[e];
    int d = A[N_EDGES + e];
    int t = etype[e];
    int seg = t * N_NODES + d;
    int slot = atomicAdd(&cnt[seg], 1);
    if (slot < CAP) ell[(size_t)seg * CAP + slot] = s;
}

template <int OUTC, bool RELU, bool BF16OUT>
__global__ __launch_bounds__(256, 3)
void rgcn_layer_mfma(const ushort* __restrict__ xbf,  // (N+1,128) bf16
                     const int* __restrict__ cnt,     // (R*N,)
                     const int* __restrict__ ell,     // (R*N,CAP)
                     const ushort* __restrict__ Wt,   // (R+1,OUTC,128) bf16
                     const float* __restrict__ bias,  // (OUTC,)
                     void* __restrict__ outp) {       // (N,OUTC)
    constexpr int LDK = 136;        // padded k-stride (272 B rows, 16B aligned)
    constexpr int TN  = 32;
    constexpr int NTW = OUTC / 32;

    __shared__ ushort meanT[TN * LDK];   // 8.7 KB
    __shared__ ushort Wl[OUTC * LDK];    // 34.8 / 17.4 KB

    const int tid   = threadIdx.x;
    const int lane  = tid & 63;
    const int wave  = tid >> 6;
    const int nbase = blockIdx.x * TN;

    // gather mapping: 16 lanes per node, lane j owns features [8j, 8j+8)
    const int g  = tid >> 4;
    const int j  = tid & 15;
    const int j8 = j * 8;
    const int gb = lane & 48;   // group base within wave (for shfl)

    // MFMA mapping
    const int rt = wave & 1;
    const int ch = wave >> 1;
    const int lr = lane & 15;
    const int kc = (lane >> 4) * 8;

    f32x4 acc[NTW];
#pragma unroll
    for (int t = 0; t < NTW; ++t) acc[t] = (f32x4){0.f, 0.f, 0.f, 0.f};

    for (int r = 0; r <= N_REL; ++r) {
        if (r) __syncthreads();

        // ---- stage W_r^T ----
        {
            const float4* src = (const float4*)(Wt + (size_t)r * OUTC * 128);
            constexpr int CH = OUTC * 16;
#pragma unroll
            for (int c = 0; c < CH / 256; ++c) {
                int idx = tid + c * 256;
                int n   = idx >> 4;
                int k8  = idx & 15;
                *(float4*)&Wl[n * LDK + k8 * 8] = src[idx];
            }
        }

        // ---- gather-mean (bf16 rows, 4-deep, zero-row padded) ----
#pragma unroll
        for (int p = 0; p < 2; ++p) {
            int a  = p * 16 + g;
            int gn = nbase + a;
            short8 sv = (short8){0, 0, 0, 0, 0, 0, 0, 0};
            if (gn < N_NODES) {
                if (r == N_REL) {
                    sv = *(const short8*)(xbf + (size_t)gn * 128 + j8);
                } else {
                    int seg = r * N_NODES + gn;
                    int c   = cnt[seg];
                    int cc  = c < CAP ? c : CAP;
                    const int* el = ell + (size_t)seg * CAP;
                    int pre0 = (j < cc) ? el[j] : N_NODES;
                    int pre1 = (16 + j < cc) ? el[16 + j] : N_NODES;
                    f32x4 s0 = (f32x4){0.f, 0.f, 0.f, 0.f};
                    f32x4 s1 = (f32x4){0.f, 0.f, 0.f, 0.f};
                    int ccr = (cc + 3) & ~3;
                    for (int e = 0; e < ccr; e += 4) {
                        int base = (e < 16) ? pre0 : pre1;
                        int i0 = __shfl(base, gb + ((e + 0) & 15), 64);
                        int i1 = __shfl(base, gb + ((e + 1) & 15), 64);
                        int i2 = __shfl(base, gb + ((e + 2) & 15), 64);
                        int i3 = __shfl(base, gb + ((e + 3) & 15), 64);
                        short8 v0 = *(const short8*)(xbf + (size_t)i0 * 128 + j8);
                        short8 v1 = *(const short8*)(xbf + (size_t)i1 * 128 + j8);
                        short8 v2 = *(const short8*)(xbf + (size_t)i2 * 128 + j8);
                        short8 v3 = *(const short8*)(xbf + (size_t)i3 * 128 + j8);
#pragma unroll
                        for (int u = 0; u < 4; ++u) {
                            short8 v = (u == 0) ? v0 : (u == 1) ? v1
                                     : (u == 2) ? v2 : v3;
                            uint4 w = __builtin_bit_cast(uint4, v);
                            s0.x += u2f(w.x << 16);
                            s0.y += u2f(w.x & 0xFFFF0000u);
                            s0.z += u2f(w.y << 16);
                            s0.w += u2f(w.y & 0xFFFF0000u);
                            s1.x += u2f(w.z << 16);
                            s1.y += u2f(w.z & 0xFFFF0000u);
                            s1.z += u2f(w.w << 16);
                            s1.w += u2f(w.w & 0xFFFF0000u);
                        }
                    }
                    float inv = 1.f / (float)(c > 1 ? c : 1);
                    s0 *= inv;
                    s1 *= inv;
                    sv = (short8){(short)f2bf(s0.x), (short)f2bf(s0.y),
                                  (short)f2bf(s0.z), (short)f2bf(s0.w),
                                  (short)f2bf(s1.x), (short)f2bf(s1.y),
                                  (short)f2bf(s1.z), (short)f2bf(s1.w)};
                }
            }
            *(short8*)&meanT[a * LDK + j8] = sv;
        }
        __syncthreads();

        // ---- MFMA ----
        short8 af[4];
        const int m = rt * 16 + lr;
#pragma unroll
        for (int ks = 0; ks < 4; ++ks)
            af[ks] = *(const short8*)&meanT[m * LDK + ks * 32 + kc];
#pragma unroll
        for (int t = 0; t < NTW; ++t) {
            const int n = (ch * NTW + t) * 16 + lr;
            f32x4 a = acc[t];
#pragma unroll
            for (int ks = 0; ks < 4; ++ks) {
                short8 bf = *(const short8*)&Wl[n * LDK + ks * 32 + kc];
                a = __builtin_amdgcn_mfma_f32_16x16x32_bf16(af[ks], bf, a, 0, 0, 0);
            }
            acc[t] = a;
        }
    }

    // ---- epilogue ----
    const int rq = (lane >> 4) * 4;
#pragma unroll
    for (int t = 0; t < NTW; ++t) {
        int col  = (ch * NTW + t) * 16 + lr;
        float bv = bias[col];
#pragma unroll
        for (int q = 0; q < 4; ++q) {
            int node = nbase + rt * 16 + rq + q;
            if (node < N_NODES) {
                float v = acc[t][q] + bv;
                if (RELU) v = fmaxf(v, 0.f);
                if (BF16OUT)
                    ((ushort*)outp)[(size_t)node * OUTC + col] = f2bf(v);
                else
                    ((float*)outp)[(size_t)node * OUTC + col] = v;
            }
        }
    }
}

extern "C" void kernel_launch(void* const* d_in, const int* in_sizes, int n_in,
                              void* d_out, int out_size, void* d_ws, size_t ws_size,
                              hipStream_t stream) {
    const float* x        = (const float*)d_in[0];
    const int*   A        = (const int*)d_in[1];
    const int*   etype    = (const int*)d_in[2];
    const float* w1_basis = (const float*)d_in[3];
    const float* w1_comp  = (const float*)d_in[4];
    const float* w1_root  = (const float*)d_in[5];
    const float* w1_bias  = (const float*)d_in[6];
    const float* w2_basis = (const float*)d_in[7];
    const float* w2_comp  = (const float*)d_in[8];
    const float* w2_root  = (const float*)d_in[9];
    const float* w2_bias  = (const float*)d_in[10];
    float* out = (float*)d_out;

    char* ws = (char*)d_ws;
    ushort* Wt1  = (ushort*)(ws);                   // 294,912 B
    ushort* Wt2  = (ushort*)(ws + (512 << 10));     // 147,456 B
    int*    cnt  = (int*)(ws + (1 << 20));          // 1.6 MB
    ushort* x_bf = (ushort*)(ws + (3ull << 20));    // 12.8 MB ((N+1)*128)
    ushort* h_bf = (ushort*)(ws + (16ull << 20));   // 12.8 MB
    int*    ell  = (int*)(ws + (29ull << 20));      // 51.2 MB

    zero_i32_kernel<<<(N_REL * N_NODES + 255) / 256, 256, 0, stream>>>(
        cnt, N_REL * N_NODES);
    to_bf16_kernel<<<((N_NODES + 1) * 16 + 255) / 256, 256, 0, stream>>>(x, x_bf);
    // zero row N of h_bf (gather sentinel for layer 2): 128 bf16 = 64 ints
    zero_i32_kernel<<<1, 64, 0, stream>>>((int*)(h_bf + (size_t)N_NODES * 128), 64);
    compose_wt_kernel<<<(9 * 128 * 128 + 255) / 256, 256, 0, stream>>>(
        w1_basis, w1_comp, w1_root, Wt1, 128, 9 * 128 * 128);
    compose_wt_kernel<<<(9 * 64 * 128 + 255) / 256, 256, 0, stream>>>(
        w2_basis, w2_comp, w2_root, Wt2, 64, 9 * 64 * 128);
    build_ell_kernel<<<(N_EDGES + 255) / 256, 256, 0, stream>>>(A, etype, cnt, ell);

    int grid = (N_NODES + 31) / 32;  // 1563
    rgcn_layer_mfma<128, true, true><<<grid, 256, 0, stream>>>(
        x_bf, cnt, ell, Wt1, w1_bias, h_bf);
    rgcn_layer_mfma<64, false, false><<<grid, 256, 0, stream>>>(
        h_bf, cnt, ell, Wt2, w2_bias, out);
}